// Round 4
// baseline (98.427 us; speedup 1.0000x reference)
//
#include <hip/hip_runtime.h>
#include <hip/hip_bf16.h>

#define CIN  64
#define HH   128
#define WW   128
#define COUT 64
#define K2   9
#define HW   (HH * WW)

typedef __attribute__((ext_vector_type(8))) short bf16x8;
typedef __attribute__((ext_vector_type(4))) float f32x4;
typedef __attribute__((ext_vector_type(2))) float f32x2;
typedef __attribute__((ext_vector_type(4))) unsigned short u16x4;
typedef __attribute__((ext_vector_type(2))) int i32x2;

__device__ __forceinline__ unsigned short f2bf(float f) {
    __hip_bfloat16 h = __float2bfloat16(f);
    return *reinterpret_cast<unsigned short*>(&h);
}
// unpack dword holding 2 bf16 (lo=ch0, hi=ch1) -> f32x2
__device__ __forceinline__ f32x2 up2(unsigned int d) {
    f32x2 r;
    r[0] = __uint_as_float(d << 16);
    r[1] = __uint_as_float(d & 0xffff0000u);
    return r;
}

// ---------------- prep: x fp32 NCHW -> bf16 NHWC ----------------
__launch_bounds__(256)
__global__ void xprep_kernel(const float* __restrict__ x, unsigned short* __restrict__ xt) {
    __shared__ float sT[64][67];
    const int t   = threadIdx.x;
    const int bid = blockIdx.x;           // b*256 + y*2 + xc
    const int b   = bid >> 8;
    const int y   = (bid >> 1) & 127;
    const int x0  = (bid & 1) << 6;
    const int lane = t & 63;
    const int cg   = t >> 6;
    #pragma unroll
    for (int cc = 0; cc < 16; ++cc) {
        int c = cg * 16 + cc;
        sT[lane][c] = x[(((b * CIN + c) * HH) + y) * WW + x0 + lane];
    }
    __syncthreads();
    const int xi = t >> 2;
    const int c0 = (t & 3) * 16;
    union { unsigned short s[16]; bf16x8 v[2]; } u;
    #pragma unroll
    for (int j = 0; j < 16; ++j) u.s[j] = f2bf(sT[xi][c0 + j]);
    unsigned short* dst = xt + ((((size_t)b * HH + y) * WW) + x0 + xi) * 64 + c0;
    *(bf16x8*)(dst)     = u.v[0];
    *(bf16x8*)(dst + 8) = u.v[1];
}

// ---------------- prep: weight fp32 [o][c][k] -> bf16 MFMA-B-fragment order ----------------
// wtp[ ((k*2+ks)*4+nt)*64*8 + l*8 + j ] = W[o=nt*16+(l&15)][c=ks*32+(l>>4)*8+j][k]
__global__ void wprep_kernel(const float* __restrict__ w, unsigned short* __restrict__ wtp) {
    int idx = blockIdx.x * 256 + threadIdx.x;
    if (idx >= COUT * CIN * K2) return;
    int j  = idx & 7;
    int l  = (idx >> 3) & 63;
    int nt = (idx >> 9) & 3;
    int ks = (idx >> 11) & 1;
    int k  = idx >> 12;
    int o  = nt * 16 + (l & 15);
    int c  = ks * 32 + (l >> 4) * 8 + j;
    wtp[idx] = f2bf(w[(o * CIN + c) * K2 + k]);
}

// ---------------- main: cross-tap software-pipelined gather + MFMA ----------------
__launch_bounds__(256, 4)
__global__ void dcn_kernel(const unsigned short* __restrict__ xt,
                           const float* __restrict__ off,
                           const unsigned short* __restrict__ wtp,
                           float* __restrict__ out) {
    __shared__ unsigned short s_s[64 * 68];     // s[pix][c] bf16, row stride 136 B
    __shared__ float s_w[2][4 * 16 * 12];       // dbuf: per-wave per-pixel {W00..W11, a0, a1}

    const int tid = threadIdx.x;
    const int w   = tid >> 6;
    const int l   = tid & 63;

    int bid = blockIdx.x;
    bid = (bid & 7) * 256 + (bid >> 3);         // XCD swizzle: one batch per XCD
    const int b   = bid >> 8;
    const int t   = bid & 255;
    const int ty0 = (t >> 4) << 3;
    const int tx0 = (t & 15) << 3;

    const int g      = l >> 4;                  // pixel subgroup
    const int lane16 = l & 15;                  // channel quad

    f32x4 acc[4] = {{0,0,0,0},{0,0,0,0},{0,0,0,0},{0,0,0,0}};

    const float* offb = off + (size_t)b * (2 * K2) * HW;
    const unsigned short* xb = xt + (size_t)b * HW * 64;

    // phase-A pixel for this lane
    const int pixA = w * 16 + lane16;
    const int ypA  = ty0 + (pixA >> 3);
    const int xpA  = tx0 + (pixA & 7);
    const int offp = ypA * WW + xpA;

    // pipeline stage registers (2 slots, compile-time indexed under full unroll)
    u16x4 C00[2][4], C01[2][4], C10[2][4], C11[2][4];
    float dyP[2], dxP[2];

    auto PHASE_A = [&](int k, int s, float dy, float dx) {
        const int kdy = k / 3 - 1, kdx = k % 3 - 1;
        float py = dy + (float)(ypA + kdy);
        float px = dx + (float)(xpA + kdx);
        float fy = floorf(py), fx = floorf(px);
        float wy = py - fy,    wx = px - fx;
        int y0  = (int)fy, x0i = (int)fx;
        int yc0 = min(max(y0,     0), HH - 1);
        int yc1 = min(max(y0 + 1, 0), HH - 1);
        float ay0 = (y0 >= 0  && y0 <= HH - 1) ? (1.f - wy) : 0.f;
        float ay1 = (y0 >= -1 && y0 <= HH - 2) ? wy         : 0.f;
        int   xL  = min(max(x0i, 0), WW - 2);
        float bx0 = (x0i >= 0  && x0i <= WW - 1) ? (1.f - wx) : 0.f;
        float bx1 = (x0i >= -1 && x0i <= WW - 2) ? wx         : 0.f;
        bool  sw  = (x0i != xL);
        float wxa = sw ? bx1 : bx0;
        float wxb = sw ? bx0 : bx1;
        f32x4 wv;
        wv[0] = ay0 * wxa; wv[1] = ay0 * wxb;
        wv[2] = ay1 * wxa; wv[3] = ay1 * wxb;
        int a0 = (yc0 * WW + xL) * 64;
        int a1 = (yc1 * WW + xL) * 64;
        if (l < 16) {
            float* wp = &s_w[s][pixA * 12];
            *(f32x4*)wp = wv;
            i32x2 av; av[0] = a0; av[1] = a1;
            *(i32x2*)(wp + 4) = av;
        }
    };

    auto GATHER = [&](int s) {                  // issue 16 corner loads into stage s
        #pragma unroll
        for (int it = 0; it < 4; ++it) {
            const float* wp = &s_w[s][(w * 16 + it * 4 + g) * 12];
            i32x2 av = *(const i32x2*)(wp + 4);
            const unsigned short* p0 = xb + av[0] + 4 * lane16;
            const unsigned short* p1 = xb + av[1] + 4 * lane16;
            C00[s][it] = *(const u16x4*)p0;
            C01[s][it] = *(const u16x4*)(p0 + 64);
            C10[s][it] = *(const u16x4*)p1;
            C11[s][it] = *(const u16x4*)(p1 + 64);
        }
    };

    auto CONSUME = [&](int k, int s) {
        // B fragments issued first (L2-resident; latency hides under interp)
        bf16x8 bv[2][4];
        #pragma unroll
        for (int ks = 0; ks < 2; ++ks)
            #pragma unroll
            for (int nt = 0; nt < 4; ++nt)
                bv[ks][nt] = *(const bf16x8*)(wtp + (((k * 2 + ks) * 4 + nt) * 64 + l) * 8);

        #pragma unroll
        for (int it = 0; it < 4; ++it) {
            const float* wp = &s_w[s][(w * 16 + it * 4 + g) * 12];
            f32x4 Wv = *(const f32x4*)wp;       // broadcast within group
            union { u16x4 h; unsigned int d[2]; } c00, c01, c10, c11;
            c00.h = C00[s][it]; c01.h = C01[s][it];
            c10.h = C10[s][it]; c11.h = C11[s][it];
            f32x2 v0 = up2(c00.d[0]) * Wv[0] + up2(c01.d[0]) * Wv[1]
                     + up2(c10.d[0]) * Wv[2] + up2(c11.d[0]) * Wv[3];
            f32x2 v1 = up2(c00.d[1]) * Wv[0] + up2(c01.d[1]) * Wv[1]
                     + up2(c10.d[1]) * Wv[2] + up2(c11.d[1]) * Wv[3];
            u16x4 r;
            r[0] = f2bf(v0[0]); r[1] = f2bf(v0[1]);
            r[2] = f2bf(v1[0]); r[3] = f2bf(v1[1]);
            *(u16x4*)(&s_s[(w * 16 + it * 4 + g) * 68 + 4 * lane16]) = r;
        }

        const int row = w * 16 + lane16;
        __builtin_amdgcn_s_setprio(1);
        #pragma unroll
        for (int ks = 0; ks < 2; ++ks) {
            const unsigned short* ap = &s_s[row * 68 + ks * 32 + g * 8];
            union { u16x4 h[2]; bf16x8 v; } af;
            af.h[0] = *(const u16x4*)ap;
            af.h[1] = *(const u16x4*)(ap + 4);
            #pragma unroll
            for (int nt = 0; nt < 4; ++nt)
                acc[nt] = __builtin_amdgcn_mfma_f32_16x16x32_bf16(af.v, bv[ks][nt], acc[nt], 0, 0, 0);
        }
        __builtin_amdgcn_s_setprio(0);
    };

    // -------- prologue --------
    dyP[0] = offb[offp];            dxP[0] = offb[HW + offp];          // tap 0
    dyP[1] = offb[2 * HW + offp];   dxP[1] = offb[3 * HW + offp];      // tap 1
    PHASE_A(0, 0, dyP[0], dxP[0]);
    GATHER(0);

    // -------- pipelined main loop --------
    #pragma unroll
    for (int k = 0; k < K2; ++k) {
        const int cur = k & 1, nxt = cur ^ 1;
        if (k + 1 < K2) {
            PHASE_A(k + 1, nxt, dyP[nxt], dxP[nxt]);
            if (k + 2 < K2) {                   // offsets for tap k+2 land in slot cur
                dyP[cur] = offb[(2 * (k + 2)    ) * HW + offp];
                dxP[cur] = offb[(2 * (k + 2) + 1) * HW + offp];
            }
            GATHER(nxt);                        // issue k+1 gathers, in flight during CONSUME(k)
        }
        CONSUME(k, cur);
    }

    // -------- epilogue: f32x4 stores (4 consecutive x per lane) --------
    const int o_lane = l & 15;
    const int rq     = (l >> 4) * 4;
    #pragma unroll
    for (int nt = 0; nt < 4; ++nt) {
        const int o   = nt * 16 + o_lane;
        const int pix = w * 16 + rq;            // j=0..3 contiguous in x, same row
        const int yy  = ty0 + (pix >> 3);
        const int xx  = tx0 + (pix & 7);
        *(f32x4*)&out[(((size_t)b * COUT + o) * HH + yy) * WW + xx] = acc[nt];
    }
}

// ---------------- fallback path (no xt room): R0 kernel ----------------
__global__ void wprep_fb(const float* __restrict__ w, unsigned short* __restrict__ wt) {
    int idx = blockIdx.x * 256 + threadIdx.x;
    if (idx >= COUT * CIN * K2) return;
    int o = idx / (CIN * K2);
    int r = idx % (CIN * K2);
    int k = r / CIN;
    int c = r % CIN;
    wt[idx] = f2bf(w[o * (CIN * K2) + c * K2 + k]);
}

__launch_bounds__(256)
__global__ void dcn_fb(const float* __restrict__ x, const float* __restrict__ off,
                       const unsigned short* __restrict__ wt, float* __restrict__ out) {
    __shared__ unsigned short s_s[64 * 66];
    const int tid = threadIdx.x;
    const int w = tid >> 6, l = tid & 63;
    const int bid = blockIdx.x;
    const int b = bid >> 8, t = bid & 255;
    const int ty0 = (t >> 4) << 3, tx0 = (t & 15) << 3;
    const int iy = l >> 3, ix = l & 7;
    const int ypix = ty0 + iy, xpix = tx0 + ix;
    f32x4 acc[4] = {{0,0,0,0},{0,0,0,0},{0,0,0,0},{0,0,0,0}};
    const int c0w = w * 16;
    for (int k = 0; k < K2; ++k) {
        float dy = off[(((b * (2*K2)) + 2*k    ) * HH + ypix) * WW + xpix];
        float dx = off[(((b * (2*K2)) + 2*k + 1) * HH + ypix) * WW + xpix];
        float py = dy + (float)(k / 3 + ypix - 1);
        float px = dx + (float)(k % 3 + xpix - 1);
        float fy = floorf(py), fx = floorf(px);
        float wy = py - fy, wx = px - fx;
        int y0 = (int)fy, x0 = (int)fx;
        int yc0 = min(max(y0, 0), HH-1), yc1 = min(max(y0+1, 0), HH-1);
        float ay0 = (y0 >= 0 && y0 <= HH-1) ? (1.f-wy) : 0.f;
        float ay1 = (y0 >= -1 && y0 <= HH-2) ? wy : 0.f;
        int xL = min(max(x0, 0), WW-2);
        float bx0 = (x0 >= 0 && x0 <= WW-1) ? (1.f-wx) : 0.f;
        float bx1 = (x0 >= -1 && x0 <= WW-2) ? wx : 0.f;
        bool sw = (x0 != xL);
        float wxa = sw ? bx1 : bx0, wxb = sw ? bx0 : bx1;
        float W0x = ay0*wxa, W0y = ay0*wxb, W1x = ay1*wxa, W1y = ay1*wxb;
        const float* r0 = x + ((b * CIN + c0w) * HH + yc0) * WW + xL;
        const float* r1 = x + ((b * CIN + c0w) * HH + yc1) * WW + xL;
        unsigned short* sd = &s_s[l * 66 + c0w];
        #pragma unroll
        for (int cc = 0; cc < 16; ++cc) {
            sd[cc] = f2bf(W0x*r0[0] + W0y*r0[1] + W1x*r1[0] + W1y*r1[1]);
            r0 += HH*WW; r1 += HH*WW;
        }
        __syncthreads();
        const int o_lane = l & 15, q = l >> 4;
        #pragma unroll
        for (int ks = 0; ks < 2; ++ks) {
            const int cb = ks*32 + q*8;
            const int row = w*16 + o_lane;
            const unsigned int* sp = (const unsigned int*)s_s;
            const int ib = row*33 + (cb >> 1);
            union { unsigned int u[4]; bf16x8 v; } af;
            af.u[0]=sp[ib]; af.u[1]=sp[ib+1]; af.u[2]=sp[ib+2]; af.u[3]=sp[ib+3];
            #pragma unroll
            for (int nt = 0; nt < 4; ++nt) {
                bf16x8 bfv = *(const bf16x8*)(wt + (nt*16 + o_lane) * (CIN*K2) + k*64 + cb);
                acc[nt] = __builtin_amdgcn_mfma_f32_16x16x32_bf16(af.v, bfv, acc[nt], 0, 0, 0);
            }
        }
        __syncthreads();
    }
    const int o_lane = l & 15, rq = (l >> 4) * 4;
    #pragma unroll
    for (int nt = 0; nt < 4; ++nt) {
        const int o = nt*16 + o_lane;
        #pragma unroll
        for (int j = 0; j < 4; ++j) {
            const int pix = w*16 + rq + j;
            out[(((size_t)b * COUT + o) * HH + ty0 + (pix>>3)) * WW + tx0 + (pix&7)] = acc[nt][j];
        }
    }
}

extern "C" void kernel_launch(void* const* d_in, const int* in_sizes, int n_in,
                              void* d_out, int out_size, void* d_ws, size_t ws_size,
                              hipStream_t stream) {
    const float* x   = (const float*)d_in[0];
    const float* off = (const float*)d_in[1];
    const float* wgt = (const float*)d_in[2];
    float* out = (float*)d_out;

    const size_t xt_bytes = (size_t)8 * HH * WW * 64 * sizeof(unsigned short); // 16 MiB
    const size_t wt_bytes = (size_t)COUT * CIN * K2 * sizeof(unsigned short);  // 72 KiB

    if (ws_size >= xt_bytes + wt_bytes) {
        unsigned short* xt  = (unsigned short*)d_ws;
        unsigned short* wtp = (unsigned short*)((char*)d_ws + xt_bytes);
        xprep_kernel<<<2048, 256, 0, stream>>>(x, xt);
        wprep_kernel<<<(COUT * CIN * K2 + 255) / 256, 256, 0, stream>>>(wgt, wtp);
        dcn_kernel<<<2048, 256, 0, stream>>>(xt, off, wtp, out);
    } else {
        unsigned short* wt = (unsigned short*)d_ws;
        wprep_fb<<<(COUT * CIN * K2 + 255) / 256, 256, 0, stream>>>(wgt, wt);
        dcn_fb<<<2048, 256, 0, stream>>>(x, off, wt, out);
    }
}

// Round 5
// 76.072 us; speedup vs baseline: 1.2939x; 1.2939x over previous
//
#include <hip/hip_runtime.h>
#include <hip/hip_bf16.h>

#define CIN  64
#define HH   128
#define WW   128
#define COUT 64
#define K2   9
#define HW   (HH * WW)

typedef __attribute__((ext_vector_type(8))) short bf16x8;
typedef __attribute__((ext_vector_type(4))) float f32x4;
typedef __attribute__((ext_vector_type(2))) float f32x2;
typedef __attribute__((ext_vector_type(4))) unsigned short u16x4;

__device__ __forceinline__ unsigned short f2bf(float f) {
    __hip_bfloat16 h = __float2bfloat16(f);
    return *reinterpret_cast<unsigned short*>(&h);
}
// unpack dword holding 2 bf16 (lo=ch0, hi=ch1) -> f32x2
__device__ __forceinline__ f32x2 up2(unsigned int d) {
    f32x2 r;
    r[0] = __uint_as_float(d << 16);
    r[1] = __uint_as_float(d & 0xffff0000u);
    return r;
}

// ---------------- prep: x fp32 NCHW -> bf16 NHWC ----------------
__launch_bounds__(256)
__global__ void xprep_kernel(const float* __restrict__ x, unsigned short* __restrict__ xt) {
    __shared__ float sT[64][67];
    const int t   = threadIdx.x;
    const int bid = blockIdx.x;           // b*256 + y*2 + xc
    const int b   = bid >> 8;
    const int y   = (bid >> 1) & 127;
    const int x0  = (bid & 1) << 6;
    const int lane = t & 63;
    const int cg   = t >> 6;
    #pragma unroll
    for (int cc = 0; cc < 16; ++cc) {
        int c = cg * 16 + cc;
        sT[lane][c] = x[(((b * CIN + c) * HH) + y) * WW + x0 + lane];
    }
    __syncthreads();
    const int xi = t >> 2;
    const int c0 = (t & 3) * 16;
    union { unsigned short s[16]; bf16x8 v[2]; } u;
    #pragma unroll
    for (int j = 0; j < 16; ++j) u.s[j] = f2bf(sT[xi][c0 + j]);
    unsigned short* dst = xt + ((((size_t)b * HH + y) * WW) + x0 + xi) * 64 + c0;
    *(bf16x8*)(dst)     = u.v[0];
    *(bf16x8*)(dst + 8) = u.v[1];
}

// ---------------- prep: weight fp32 [o][c][k] -> bf16 MFMA-B-fragment order ----------------
// wtp[ ((k*2+ks)*4+nt)*64*8 + l*8 + j ] = W[o=nt*16+(l&15)][c=ks*32+(l>>4)*8+j][k]
__global__ void wprep_kernel(const float* __restrict__ w, unsigned short* __restrict__ wtp) {
    int idx = blockIdx.x * 256 + threadIdx.x;
    if (idx >= COUT * CIN * K2) return;
    int j  = idx & 7;
    int l  = (idx >> 3) & 63;
    int nt = (idx >> 9) & 3;
    int ks = (idx >> 11) & 1;
    int k  = idx >> 12;
    int o  = nt * 16 + (l & 15);
    int c  = ks * 32 + (l >> 4) * 8 + j;
    wtp[idx] = f2bf(w[(o * CIN + c) * K2 + k]);
}

// ---------------- main: spill-safe single-stage pipelined gather + MFMA ----------------
__launch_bounds__(256, 3)
__global__ void dcn_kernel(const unsigned short* __restrict__ xt,
                           const float* __restrict__ off,
                           const unsigned short* __restrict__ wtp,
                           float* __restrict__ out) {
    __shared__ unsigned short s_s[64 * 68];     // s[pix][c] bf16, row stride 136 B

    const int tid = threadIdx.x;
    const int w   = tid >> 6;
    const int l   = tid & 63;

    int bid = blockIdx.x;
    bid = (bid & 7) * 256 + (bid >> 3);         // XCD swizzle: one batch per XCD
    const int b   = bid >> 8;
    const int t   = bid & 255;
    const int ty0 = (t >> 4) << 3;
    const int tx0 = (t & 15) << 3;

    const int g      = l >> 4;                  // pixel subgroup
    const int lane16 = l & 15;                  // channel quad
    const int row    = w * 16 + lane16;         // A-fragment row (pixel)

    f32x4 acc[4] = {{0,0,0,0},{0,0,0,0},{0,0,0,0},{0,0,0,0}};

    const float* offb = off + (size_t)b * (2 * K2) * HW;
    const unsigned short* xb = xt + (size_t)b * HW * 64;

    // phase-A pixel for this lane (every lane computes pixel lane16's params)
    const int pixA = w * 16 + lane16;
    const int ypA  = ty0 + (pixA >> 3);
    const int xpA  = tx0 + (pixA & 7);
    const int offp = ypA * WW + xpA;

    // ---- pipeline state: ALL literal-indexed (spill-safe) ----
    u16x4 stg00[4], stg01[4], stg10[4], stg11[4];   // single gather stage (32 VGPR)
    f32x4 Pw[2];                                     // bilinear weights, slot 0/1
    int   Pa0[2], Pa1[2];                            // corner-row element offsets
    float oyv[2], oxv[2];                            // prefetched raw offsets
    bf16x8 bv[2][4];                                 // B fragments for current tap

#define PARAMS(K, S) do {                                                     \
    const int kdy = (K) / 3 - 1, kdx = (K) % 3 - 1;                           \
    float py = oyv[S] + (float)(ypA + kdy);                                   \
    float px = oxv[S] + (float)(xpA + kdx);                                   \
    float fy = floorf(py), fx = floorf(px);                                   \
    float wy = py - fy, wxn = px - fx;                                        \
    int y0 = (int)fy, x0i = (int)fx;                                          \
    int yc0 = min(max(y0,     0), HH - 1);                                    \
    int yc1 = min(max(y0 + 1, 0), HH - 1);                                    \
    float ay0 = (y0 >= 0  && y0 <= HH - 1) ? (1.f - wy) : 0.f;                \
    float ay1 = (y0 >= -1 && y0 <= HH - 2) ? wy         : 0.f;                \
    int   xL  = min(max(x0i, 0), WW - 2);                                     \
    float bx0 = (x0i >= 0  && x0i <= WW - 1) ? (1.f - wxn) : 0.f;             \
    float bx1 = (x0i >= -1 && x0i <= WW - 2) ? wxn         : 0.f;             \
    bool  sw  = (x0i != xL);                                                  \
    float wxa = sw ? bx1 : bx0;                                               \
    float wxb = sw ? bx0 : bx1;                                               \
    Pw[S][0] = ay0 * wxa; Pw[S][1] = ay0 * wxb;                               \
    Pw[S][2] = ay1 * wxa; Pw[S][3] = ay1 * wxb;                               \
    Pa0[S] = (yc0 * WW + xL) * 64;                                            \
    Pa1[S] = (yc1 * WW + xL) * 64;                                            \
} while (0)

#define GATHER(S) do {                                                        \
    _Pragma("unroll")                                                         \
    for (int it = 0; it < 4; ++it) {                                          \
        int a0 = __shfl(Pa0[S], it * 4 + g, 16);                              \
        int a1 = __shfl(Pa1[S], it * 4 + g, 16);                              \
        const unsigned short* p0 = xb + a0 + 4 * lane16;                      \
        const unsigned short* p1 = xb + a1 + 4 * lane16;                      \
        stg00[it] = *(const u16x4*)p0;                                        \
        stg01[it] = *(const u16x4*)(p0 + 64);                                 \
        stg10[it] = *(const u16x4*)p1;                                        \
        stg11[it] = *(const u16x4*)(p1 + 64);                                 \
    }                                                                         \
} while (0)

#define INTERP(K, S) do {                                                     \
    _Pragma("unroll")                                                         \
    for (int ks = 0; ks < 2; ++ks)                                            \
        _Pragma("unroll")                                                     \
        for (int nt = 0; nt < 4; ++nt)                                        \
            bv[ks][nt] = *(const bf16x8*)(wtp + ((((K)*2 + ks)*4 + nt)*64 + l)*8); \
    _Pragma("unroll")                                                         \
    for (int it = 0; it < 4; ++it) {                                          \
        f32x4 Wv;                                                             \
        Wv[0] = __shfl(Pw[S][0], it * 4 + g, 16);                             \
        Wv[1] = __shfl(Pw[S][1], it * 4 + g, 16);                             \
        Wv[2] = __shfl(Pw[S][2], it * 4 + g, 16);                             \
        Wv[3] = __shfl(Pw[S][3], it * 4 + g, 16);                             \
        union { u16x4 h; unsigned int d[2]; } c00, c01, c10, c11;             \
        c00.h = stg00[it]; c01.h = stg01[it];                                 \
        c10.h = stg10[it]; c11.h = stg11[it];                                 \
        f32x2 v0 = up2(c00.d[0]) * Wv[0] + up2(c01.d[0]) * Wv[1]              \
                 + up2(c10.d[0]) * Wv[2] + up2(c11.d[0]) * Wv[3];             \
        f32x2 v1 = up2(c00.d[1]) * Wv[0] + up2(c01.d[1]) * Wv[1]              \
                 + up2(c10.d[1]) * Wv[2] + up2(c11.d[1]) * Wv[3];             \
        u16x4 r;                                                              \
        r[0] = f2bf(v0[0]); r[1] = f2bf(v0[1]);                               \
        r[2] = f2bf(v1[0]); r[3] = f2bf(v1[1]);                               \
        *(u16x4*)(&s_s[(w * 16 + it * 4 + g) * 68 + 4 * lane16]) = r;         \
    }                                                                         \
} while (0)

#define DOMFMA(K) do {                                                        \
    __builtin_amdgcn_s_setprio(1);                                            \
    _Pragma("unroll")                                                         \
    for (int ks = 0; ks < 2; ++ks) {                                          \
        const unsigned short* ap = &s_s[row * 68 + ks * 32 + g * 8];          \
        union { u16x4 h[2]; bf16x8 v; } af;                                   \
        af.h[0] = *(const u16x4*)ap;                                          \
        af.h[1] = *(const u16x4*)(ap + 4);                                    \
        _Pragma("unroll")                                                     \
        for (int nt = 0; nt < 4; ++nt)                                        \
            acc[nt] = __builtin_amdgcn_mfma_f32_16x16x32_bf16(af.v, bv[ks][nt], acc[nt], 0, 0, 0); \
    }                                                                         \
    __builtin_amdgcn_s_setprio(0);                                            \
} while (0)

// steady-state step: params(k+1) -> prefetch offsets(k+2) -> interp(k) ->
// gather(k+1) [in flight across MFMA(k) + next params] -> MFMA(k)
#define STEP(K, CUR, NXT) do {                                                \
    PARAMS((K) + 1, NXT);                                                     \
    if ((K) + 2 < K2) {                                                       \
        oyv[CUR] = offb[(2 * ((K) + 2)    ) * HW + offp];                     \
        oxv[CUR] = offb[(2 * ((K) + 2) + 1) * HW + offp];                     \
    }                                                                         \
    INTERP(K, CUR);                                                           \
    GATHER(NXT);                                                              \
    DOMFMA(K);                                                                \
} while (0)

    // -------- prologue --------
    oyv[0] = offb[offp];          oxv[0] = offb[HW + offp];
    oyv[1] = offb[2 * HW + offp]; oxv[1] = offb[3 * HW + offp];
    PARAMS(0, 0);
    GATHER(0);

    // -------- fully-explicit pipelined taps --------
    STEP(0, 0, 1); STEP(1, 1, 0); STEP(2, 0, 1); STEP(3, 1, 0);
    STEP(4, 0, 1); STEP(5, 1, 0); STEP(6, 0, 1); STEP(7, 1, 0);
    // tail: tap 8 (params in slot 0, stage filled by STEP(7))
    INTERP(8, 0);
    DOMFMA(8);

#undef PARAMS
#undef GATHER
#undef INTERP
#undef DOMFMA
#undef STEP

    // -------- epilogue: f32x4 stores (4 consecutive x per lane, 16B aligned) --------
    const int o_lane = l & 15;
    const int rq     = (l >> 4) * 4;
    #pragma unroll
    for (int nt = 0; nt < 4; ++nt) {
        const int o   = nt * 16 + o_lane;
        const int pix = w * 16 + rq;
        const int yy  = ty0 + (pix >> 3);
        const int xx  = tx0 + (pix & 7);
        *(f32x4*)&out[(((size_t)b * COUT + o) * HH + yy) * WW + xx] = acc[nt];
    }
}

// ---------------- fallback path (no xt room): R0 kernel ----------------
__global__ void wprep_fb(const float* __restrict__ w, unsigned short* __restrict__ wt) {
    int idx = blockIdx.x * 256 + threadIdx.x;
    if (idx >= COUT * CIN * K2) return;
    int o = idx / (CIN * K2);
    int r = idx % (CIN * K2);
    int k = r / CIN;
    int c = r % CIN;
    wt[idx] = f2bf(w[o * (CIN * K2) + c * K2 + k]);
}

__launch_bounds__(256)
__global__ void dcn_fb(const float* __restrict__ x, const float* __restrict__ off,
                       const unsigned short* __restrict__ wt, float* __restrict__ out) {
    __shared__ unsigned short s_s[64 * 66];
    const int tid = threadIdx.x;
    const int w = tid >> 6, l = tid & 63;
    const int bid = blockIdx.x;
    const int b = bid >> 8, t = bid & 255;
    const int ty0 = (t >> 4) << 3, tx0 = (t & 15) << 3;
    const int iy = l >> 3, ix = l & 7;
    const int ypix = ty0 + iy, xpix = tx0 + ix;
    f32x4 acc[4] = {{0,0,0,0},{0,0,0,0},{0,0,0,0},{0,0,0,0}};
    const int c0w = w * 16;
    for (int k = 0; k < K2; ++k) {
        float dy = off[(((b * (2*K2)) + 2*k    ) * HH + ypix) * WW + xpix];
        float dx = off[(((b * (2*K2)) + 2*k + 1) * HH + ypix) * WW + xpix];
        float py = dy + (float)(k / 3 + ypix - 1);
        float px = dx + (float)(k % 3 + xpix - 1);
        float fy = floorf(py), fx = floorf(px);
        float wy = py - fy, wx = px - fx;
        int y0 = (int)fy, x0 = (int)fx;
        int yc0 = min(max(y0, 0), HH-1), yc1 = min(max(y0+1, 0), HH-1);
        float ay0 = (y0 >= 0 && y0 <= HH-1) ? (1.f-wy) : 0.f;
        float ay1 = (y0 >= -1 && y0 <= HH-2) ? wy : 0.f;
        int xL = min(max(x0, 0), WW-2);
        float bx0 = (x0 >= 0 && x0 <= WW-1) ? (1.f-wx) : 0.f;
        float bx1 = (x0 >= -1 && x0 <= WW-2) ? wx : 0.f;
        bool sw = (x0 != xL);
        float wxa = sw ? bx1 : bx0, wxb = sw ? bx0 : bx1;
        float W0x = ay0*wxa, W0y = ay0*wxb, W1x = ay1*wxa, W1y = ay1*wxb;
        const float* r0 = x + ((b * CIN + c0w) * HH + yc0) * WW + xL;
        const float* r1 = x + ((b * CIN + c0w) * HH + yc1) * WW + xL;
        unsigned short* sd = &s_s[l * 66 + c0w];
        #pragma unroll
        for (int cc = 0; cc < 16; ++cc) {
            sd[cc] = f2bf(W0x*r0[0] + W0y*r0[1] + W1x*r1[0] + W1y*r1[1]);
            r0 += HH*WW; r1 += HH*WW;
        }
        __syncthreads();
        const int o_lane = l & 15, q = l >> 4;
        #pragma unroll
        for (int ks = 0; ks < 2; ++ks) {
            const int cb = ks*32 + q*8;
            const int row = w*16 + o_lane;
            const unsigned int* sp = (const unsigned int*)s_s;
            const int ib = row*33 + (cb >> 1);
            union { unsigned int u[4]; bf16x8 v; } af;
            af.u[0]=sp[ib]; af.u[1]=sp[ib+1]; af.u[2]=sp[ib+2]; af.u[3]=sp[ib+3];
            #pragma unroll
            for (int nt = 0; nt < 4; ++nt) {
                bf16x8 bfv = *(const bf16x8*)(wt + (nt*16 + o_lane) * (CIN*K2) + k*64 + cb);
                acc[nt] = __builtin_amdgcn_mfma_f32_16x16x32_bf16(af.v, bfv, acc[nt], 0, 0, 0);
            }
        }
        __syncthreads();
    }
    const int o_lane = l & 15, rq = (l >> 4) * 4;
    #pragma unroll
    for (int nt = 0; nt < 4; ++nt) {
        const int o = nt*16 + o_lane;
        #pragma unroll
        for (int j = 0; j < 4; ++j) {
            const int pix = w*16 + rq + j;
            out[(((size_t)b * COUT + o) * HH + ty0 + (pix>>3)) * WW + tx0 + (pix&7)] = acc[nt][j];
        }
    }
}

extern "C" void kernel_launch(void* const* d_in, const int* in_sizes, int n_in,
                              void* d_out, int out_size, void* d_ws, size_t ws_size,
                              hipStream_t stream) {
    const float* x   = (const float*)d_in[0];
    const float* off = (const float*)d_in[1];
    const float* wgt = (const float*)d_in[2];
    float* out = (float*)d_out;

    const size_t xt_bytes = (size_t)8 * HH * WW * 64 * sizeof(unsigned short); // 16 MiB
    const size_t wt_bytes = (size_t)COUT * CIN * K2 * sizeof(unsigned short);  // 72 KiB

    if (ws_size >= xt_bytes + wt_bytes) {
        unsigned short* xt  = (unsigned short*)d_ws;
        unsigned short* wtp = (unsigned short*)((char*)d_ws + xt_bytes);
        xprep_kernel<<<2048, 256, 0, stream>>>(x, xt);
        wprep_kernel<<<(COUT * CIN * K2 + 255) / 256, 256, 0, stream>>>(wgt, wtp);
        dcn_kernel<<<2048, 256, 0, stream>>>(xt, off, wtp, out);
    } else {
        unsigned short* wt = (unsigned short*)d_ws;
        wprep_fb<<<(COUT * CIN * K2 + 255) / 256, 256, 0, stream>>>(wgt, wt);
        dcn_fb<<<2048, 256, 0, stream>>>(x, off, wt, out);
    }
}